// Round 14
// baseline (284.900 us; speedup 1.0000x reference)
//
#include <hip/hip_runtime.h>

// ---------------------------------------------------------------------------
// GATEncoder fused pipeline. R13 (from R12's passing 275.7 µs / absmax 7.8e-3):
//  - dec1 mgemm<3> now 2-pass (AhWh + AhWl; A-lo dropped, err ~+0.002).
//    skip mgemm<2> no longer writes outb_lo (outLo=nullptr).
//  - enc1 GEMM + LayerNorm + ReLU + bf16 split fused into one kernel
//    (full-width BN=256 tile, per-row 32-lane shuffle reduce).
//  - detect + 4 weight splits merged into one prep_kernel.
// Launches: 17 -> 13. Everything else unchanged from R12.
// ---------------------------------------------------------------------------

#define N_NODES  10000
#define N_EDGES  160000
#define E_TOT    (N_EDGES + N_NODES)
#define NBATCH   8192
#define DIM_IN   128
#define DIM_H    256
#define DIM_GAT  512
#define DIM_DEC  1024
#define MPAD     10112                 // 79 * 128

typedef short bf16x8 __attribute__((ext_vector_type(8)));   // 8 bf16 in 4 VGPRs
typedef float f32x4  __attribute__((ext_vector_type(4)));

__device__ __forceinline__ ushort f2bf(float f) {
    union { float f; unsigned u; } c; c.f = f;
    unsigned u = c.u + 0x7FFFu + ((c.u >> 16) & 1u);   // RNE
    return (ushort)(u >> 16);
}
__device__ __forceinline__ float bf2f(ushort h) {
    union { unsigned u; float f; } c; c.u = ((unsigned)h) << 16; return c.f;
}

// ---------------------------------------------------------------------------
// enc1 + LayerNorm + ReLU + bf16 hi/lo split, fully fused.
// [10000,128] @ [128->256] + b1, then per-row LN over the full 256 cols.
// BM=64, BN=256 (full width), BK=16, TM=8, TN=8 -> TX=32, TY=8.
// For fixed (ty,i) the 32 tx-threads are contiguous lanes (half-wave), so
// shfl_xor 1..16 reduces the row.
// ---------------------------------------------------------------------------
__global__ __launch_bounds__(256)
void enc1_ln_kernel(const float* __restrict__ A, const float* __restrict__ W,
                    const float* __restrict__ bias,
                    const float* __restrict__ g, const float* __restrict__ b,
                    ushort* __restrict__ hi, ushort* __restrict__ lo)
{
    constexpr int BM = 64, BN = 256, BK = 16, TM = 8, TN = 8, TX = 32;
    constexpr int KQ = BK / 4;
    __shared__ float As[BK][BM + 4];
    __shared__ float Ws[BK][BN + 4];

    const int tid = threadIdx.x;
    const int tx  = tid % TX;
    const int ty  = tid / TX;
    const int bm  = blockIdx.x * BM;

    float acc[TM][TN];
    #pragma unroll
    for (int i = 0; i < TM; ++i)
        #pragma unroll
        for (int j = 0; j < TN; ++j) acc[i][j] = 0.f;

    for (int k0 = 0; k0 < DIM_IN; k0 += BK) {
        {   // A: 64*16/4 = 256 float4 loads, 1/thread
            int row = tid / KQ, kq = tid % KQ;
            int grow = bm + row;
            float4 v = make_float4(0.f, 0.f, 0.f, 0.f);
            if (grow < N_NODES)
                v = *reinterpret_cast<const float4*>(&A[(size_t)grow * DIM_IN + k0 + kq * 4]);
            As[kq * 4 + 0][row] = v.x; As[kq * 4 + 1][row] = v.y;
            As[kq * 4 + 2][row] = v.z; As[kq * 4 + 3][row] = v.w;
        }
        #pragma unroll
        for (int l = 0; l < 4; ++l) {   // W: 256*16/4 = 1024 float4, 4/thread
            int idx = tid + l * 256, row = idx / KQ, kq = idx % KQ;
            float4 v = *reinterpret_cast<const float4*>(&W[(size_t)row * DIM_IN + k0 + kq * 4]);
            Ws[kq * 4 + 0][row] = v.x; Ws[kq * 4 + 1][row] = v.y;
            Ws[kq * 4 + 2][row] = v.z; Ws[kq * 4 + 3][row] = v.w;
        }
        __syncthreads();
        #pragma unroll
        for (int kk = 0; kk < BK; ++kk) {
            float af[TM], wf[TN];
            #pragma unroll
            for (int i = 0; i < TM; ++i) af[i] = As[kk][ty * TM + i];
            #pragma unroll
            for (int j = 0; j < TN; ++j) wf[j] = Ws[kk][tx * TN + j];
            #pragma unroll
            for (int i = 0; i < TM; ++i)
                #pragma unroll
                for (int j = 0; j < TN; ++j)
                    acc[i][j] = fmaf(af[i], wf[j], acc[i][j]);
        }
        __syncthreads();
    }

    // epilogue: +bias, LN across the 32 tx-lanes, ReLU, hi/lo split
    #pragma unroll
    for (int i = 0; i < TM; ++i) {
        int grow = bm + ty * TM + i;
        float vals[TN];
        float s = 0.f, sq = 0.f;
        #pragma unroll
        for (int j = 0; j < TN; ++j) {
            float v = acc[i][j] + bias[tx * TN + j];
            vals[j] = v; s += v; sq += v * v;
        }
        #pragma unroll
        for (int m = 1; m <= 16; m <<= 1) { s += __shfl_xor(s, m); sq += __shfl_xor(sq, m); }
        float mu  = s * (1.0f / 256.0f);
        float var = sq * (1.0f / 256.0f) - mu * mu;
        float rs  = 1.0f / sqrtf(var + 1e-5f);
        if (grow < N_NODES) {
            ushort4 vh[2], vl[2];
            ushort* ph = (ushort*)vh; ushort* pl = (ushort*)vl;
            #pragma unroll
            for (int j = 0; j < TN; ++j) {
                int col = tx * TN + j;
                float o = fmaxf((vals[j] - mu) * rs * g[col] + b[col], 0.f);
                ushort hh = f2bf(o);
                ph[j] = hh;
                pl[j] = f2bf(o - bf2f(hh));
            }
            *reinterpret_cast<ushort4*>(&hi[(size_t)grow * DIM_H + tx * TN])     = vh[0];
            *reinterpret_cast<ushort4*>(&hi[(size_t)grow * DIM_H + tx * TN + 4]) = vh[1];
            *reinterpret_cast<ushort4*>(&lo[(size_t)grow * DIM_H + tx * TN])     = vl[0];
            *reinterpret_cast<ushort4*>(&lo[(size_t)grow * DIM_H + tx * TN + 4]) = vl[1];
        }
    }
}

// ---------------------------------------------------------------------------
// Split-bf16 MFMA GEMM: C[M,N] = A[M,K] @ W[N,K]^T.
// 128x128x64 tile, 4 waves (2x2). 3-pass hi/lo (AhWh+AhWl+AlWh) except
// EPI==3 which is 2-pass (A-lo dropped; Al must be nullptr).
// LDS tiles [128 rows][64 bf16], 16B-chunk XOR swizzle byte^=((row&7)<<4).
// EPI: 0 = bf16 xs out + fused attn-coef partials (gat);
//      1 = +bias, split hi/lo out (enc2);
//      2 = +bias+bias2+addmat, ELU(0.1), hi out (+lo if outLo) (skip);
//      3 = +bias, leaky(0.1), fused dot-with-w2 -> atomicAdd y (dec1+dec2).
// ---------------------------------------------------------------------------
__device__ __forceinline__ void stage_tile(ushort* T, const ushort* __restrict__ G,
                                           int rowbase, int K, int k0, int tid, int wv)
{
    #pragma unroll
    for (int i = 0; i < 4; ++i) {
        int m   = i * 32 + (tid >> 3);                       // tile row
        int scb = ((tid & 7) << 4) ^ ((m & 7) << 4);         // src col byte (inv swz)
        const char* gsrc = (const char*)G + ((size_t)(rowbase + m) * K + k0) * 2 + scb;
        char* ldst = (char*)T + i * 4096 + wv * 1024;        // wave-uniform base
        __builtin_amdgcn_global_load_lds(
            (const __attribute__((address_space(1))) void*)gsrc,
            (__attribute__((address_space(3))) void*)ldst, 16, 0, 0);
    }
}

__device__ __forceinline__ bf16x8 ldfrag(const ushort* T, int row, int kcb)
{
    int addr = (row << 7) + (kcb ^ ((row & 7) << 4));        // swizzled read
    return *reinterpret_cast<const bf16x8*>(reinterpret_cast<const char*>(T) + addr);
}

template<int EPI>
__global__ __launch_bounds__(256, 2)
void mgemm(const ushort* __restrict__ Ah, const ushort* __restrict__ Al,
           const ushort* __restrict__ Wh, const ushort* __restrict__ Wl,
           const float* __restrict__ bias, const float* __restrict__ bias2,
           const float* __restrict__ addmat, float* __restrict__ outF,
           ushort* __restrict__ outHi, ushort* __restrict__ outLo,
           const float* __restrict__ w2, const float* __restrict__ b2,
           float* __restrict__ aS, float* __restrict__ aD,
           float* __restrict__ yout, int M, int N, int K)
{
    __shared__ __align__(16) ushort tAh[8192];
    __shared__ __align__(16) ushort tAl[8192];
    __shared__ __align__(16) ushort tWh[8192];
    __shared__ __align__(16) ushort tWl[8192];

    const int tid    = threadIdx.x;
    const int lane   = tid & 63;
    const int wv     = tid >> 6;
    const int wr     = wv >> 1, wc = wv & 1;
    const int bm     = blockIdx.x * 128;
    const int bn     = blockIdx.y * 128;
    const int lane15 = lane & 15;
    const int kgrp16 = (lane >> 4) << 4;      // byte offset of lane's k-slice
    const int r0     = (lane >> 4) << 2;      // C/D row group

    f32x4 acc[4][4];
    const f32x4 zero = {0.f, 0.f, 0.f, 0.f};
    #pragma unroll
    for (int i = 0; i < 4; ++i)
        #pragma unroll
        for (int j = 0; j < 4; ++j) acc[i][j] = zero;

    for (int k0 = 0; k0 < K; k0 += 64) {
        stage_tile(tAh, Ah, bm, K, k0, tid, wv);
        if (EPI != 3) stage_tile(tAl, Al, bm, K, k0, tid, wv);
        stage_tile(tWh, Wh, bn, K, k0, tid, wv);
        stage_tile(tWl, Wl, bn, K, k0, tid, wv);
        __syncthreads();                       // drains vmcnt before barrier
        #pragma unroll
        for (int kk = 0; kk < 2; ++kk) {
            const int kcb = kk * 64 + kgrp16;
            bf16x8 ah[4], al[4], wh[4], wl[4];
            #pragma unroll
            for (int f = 0; f < 4; ++f) {
                ah[f] = ldfrag(tAh, wr * 64 + f * 16 + lane15, kcb);
                if (EPI != 3) al[f] = ldfrag(tAl, wr * 64 + f * 16 + lane15, kcb);
                wh[f] = ldfrag(tWh, wc * 64 + f * 16 + lane15, kcb);
                wl[f] = ldfrag(tWl, wc * 64 + f * 16 + lane15, kcb);
            }
            #pragma unroll
            for (int fm = 0; fm < 4; ++fm)
                #pragma unroll
                for (int fn = 0; fn < 4; ++fn) {
                    acc[fm][fn] = __builtin_amdgcn_mfma_f32_16x16x32_bf16(ah[fm], wh[fn], acc[fm][fn], 0, 0, 0);
                    acc[fm][fn] = __builtin_amdgcn_mfma_f32_16x16x32_bf16(ah[fm], wl[fn], acc[fm][fn], 0, 0, 0);
                    if (EPI != 3)
                        acc[fm][fn] = __builtin_amdgcn_mfma_f32_16x16x32_bf16(al[fm], wh[fn], acc[fm][fn], 0, 0, 0);
                }
        }
        __syncthreads();
    }

    if (EPI == 0) {
        // gat: write bf16 xs + fused attention partial dots.
        // bias = att_src[512], bias2 = att_dst[512]; head uniform per block.
        const int head = bn >> 8;
        #pragma unroll
        for (int fm = 0; fm < 4; ++fm) {
            #pragma unroll
            for (int r = 0; r < 4; ++r) {
                int row = bm + wr * 64 + fm * 16 + r0 + r;
                if (row < M) {          // row uniform within 16-lane group
                    float sp = 0.f, dp = 0.f;
                    #pragma unroll
                    for (int fn = 0; fn < 4; ++fn) {
                        int col = bn + wc * 64 + fn * 16 + lane15;
                        float v = acc[fm][fn][r];
                        outHi[(size_t)row * N + col] = f2bf(v);
                        sp = fmaf(v, bias[col], sp);
                        dp = fmaf(v, bias2[col], dp);
                    }
                    sp += __shfl_xor(sp, 1); sp += __shfl_xor(sp, 2);
                    sp += __shfl_xor(sp, 4); sp += __shfl_xor(sp, 8);
                    dp += __shfl_xor(dp, 1); dp += __shfl_xor(dp, 2);
                    dp += __shfl_xor(dp, 4); dp += __shfl_xor(dp, 8);
                    if (lane15 == 0) {
                        atomicAdd(&aS[row * 2 + head], sp);
                        atomicAdd(&aD[row * 2 + head], dp);
                    }
                }
            }
        }
    } else if (EPI == 1 || EPI == 2) {
        #pragma unroll
        for (int fm = 0; fm < 4; ++fm) {
            #pragma unroll
            for (int r = 0; r < 4; ++r) {
                int row = bm + wr * 64 + fm * 16 + r0 + r;
                if (row < M) {
                    #pragma unroll
                    for (int fn = 0; fn < 4; ++fn) {
                        int col = bn + wc * 64 + fn * 16 + lane15;
                        float v = acc[fm][fn][r] + bias[col];
                        if (EPI == 2) {
                            v += bias2[col] + addmat[(size_t)row * N + col];
                            v = v > 0.f ? v : 0.1f * (expf(v) - 1.f);
                        }
                        ushort h = f2bf(v);
                        outHi[(size_t)row * N + col] = h;
                        if (outLo) outLo[(size_t)row * N + col] = f2bf(v - bf2f(h));
                    }
                }
            }
        }
    } else {
        // dec1 + fused dec2: y[row] += sum_col leaky(acc+b1)[col] * w2[col]
        #pragma unroll
        for (int fm = 0; fm < 4; ++fm) {
            #pragma unroll
            for (int r = 0; r < 4; ++r) {
                int row = bm + wr * 64 + fm * 16 + r0 + r;
                float part = 0.f;
                #pragma unroll
                for (int fn = 0; fn < 4; ++fn) {
                    int col = bn + wc * 64 + fn * 16 + lane15;
                    float v = acc[fm][fn][r] + bias[col];
                    v = v > 0.f ? v : 0.1f * v;
                    part = fmaf(v, w2[col], part);
                }
                part += __shfl_xor(part, 1);
                part += __shfl_xor(part, 2);
                part += __shfl_xor(part, 4);
                part += __shfl_xor(part, 8);
                if (lane15 == 0 && row < M) {
                    // b2 exactly once per row: only the wc==0 wave of y-block 0
                    float add = part + ((blockIdx.y == 0 && wc == 0) ? b2[0] : 0.f);
                    atomicAdd(&yout[row], add);
                }
            }
        }
    }
}

// ---------------------------------------------------------------------------
// prep: edge_index dtype detection + all 4 weight hi/lo splits in one launch.
// Ranges: [0,65536) enc_w2 | [65536,196608) gat_w | [196608,327680) skip_w |
//         [327680,851968) dec_w1.
// ---------------------------------------------------------------------------
__global__ __launch_bounds__(256)
void prep_kernel(const int* __restrict__ ei32, int* __restrict__ eflag,
                 const float* __restrict__ s0, ushort* __restrict__ h0, ushort* __restrict__ l0,
                 const float* __restrict__ s1, ushort* __restrict__ h1p, ushort* __restrict__ l1,
                 const float* __restrict__ s2, ushort* __restrict__ h2, ushort* __restrict__ l2,
                 const float* __restrict__ s3, ushort* __restrict__ h3, ushort* __restrict__ l3)
{
    int i = blockIdx.x * 256 + threadIdx.x;
    if (i == 0) {
        int s = 0;
        #pragma unroll
        for (int q = 0; q < 64; ++q) s |= ei32[2 * q + 1];
        eflag[0] = (s == 0) ? 2 : 1;
    }
    const float* s; ushort* ph; ushort* pl; int off;
    if      (i < 65536)  { s = s0; ph = h0;  pl = l0; off = i; }
    else if (i < 196608) { s = s1; ph = h1p; pl = l1; off = i - 65536; }
    else if (i < 327680) { s = s2; ph = h2;  pl = l2; off = i - 196608; }
    else if (i < 851968) { s = s3; ph = h3;  pl = l3; off = i - 327680; }
    else return;
    float v = s[off];
    ushort hh = f2bf(v);
    ph[off] = hh;
    pl[off] = f2bf(v - bf2f(hh));
}

// ---------------------------------------------------------------------------
// Edge pass: w = exp(leaky(a_src[src]+a_dst[tgt],0.2)); z[tgt]+=w; counts++.
// Max-subtraction skipped: alpha = w/z is identical; |e| bounded ~2 here.
// ---------------------------------------------------------------------------
__global__ __launch_bounds__(256)
void edge_w_kernel(const int* __restrict__ ei, const int* __restrict__ eflag,
                   const float* __restrict__ asrc, const float* __restrict__ adst,
                   float* __restrict__ wbuf, float* __restrict__ zbuf,
                   int* __restrict__ counts)
{
    int e = blockIdx.x * 256 + threadIdx.x;
    if (e >= E_TOT) return;
    const int stride = eflag[0];
    int src, tgt;
    if (e < N_EDGES) {
        src = ei[(size_t)stride * e];
        tgt = ei[(size_t)stride * (N_EDGES + e)];
    } else {
        src = tgt = e - N_EDGES;
    }
    #pragma unroll
    for (int hh = 0; hh < 2; ++hh) {
        float v = asrc[src * 2 + hh] + adst[tgt * 2 + hh];
        v = v > 0.f ? v : 0.2f * v;
        float w = expf(v);
        wbuf[e * 2 + hh] = w;
        atomicAdd(&zbuf[tgt * 2 + hh], w);
    }
    atomicAdd(&counts[tgt], 1);
}

// ---------------------------------------------------------------------------
// Exclusive prefix sum counts -> rowst. One block.
// ---------------------------------------------------------------------------
__global__ __launch_bounds__(1024)
void scan_kernel(const int* __restrict__ counts, int* __restrict__ rowst)
{
    __shared__ int part[1024];
    const int t = threadIdx.x;
    const int base = t * 10;
    int loc[10];
    int s = 0;
    #pragma unroll
    for (int i = 0; i < 10; ++i) {
        int idx = base + i;
        int v = (idx < N_NODES) ? counts[idx] : 0;
        loc[i] = s;
        s += v;
    }
    part[t] = s;
    __syncthreads();
    for (int off = 1; off < 1024; off <<= 1) {
        int v = (t >= off) ? part[t - off] : 0;
        __syncthreads();
        part[t] += v;
        __syncthreads();
    }
    int chunk_excl = part[t] - s;
    #pragma unroll
    for (int i = 0; i < 10; ++i) {
        int idx = base + i;
        if (idx <= N_NODES) rowst[idx] = chunk_excl + loc[i];
    }
}

// ---------------------------------------------------------------------------
// Scatter packed (e<<14)|src (unsigned!) into CSR buckets by target.
// ---------------------------------------------------------------------------
__global__ __launch_bounds__(256)
void scatter_kernel(const int* __restrict__ ei, const int* __restrict__ eflag,
                    const int* __restrict__ rowst,
                    int* __restrict__ cursor, unsigned int* __restrict__ ebuf)
{
    int e = blockIdx.x * 256 + threadIdx.x;
    if (e >= E_TOT) return;
    const int stride = eflag[0];
    int src, tgt;
    if (e < N_EDGES) {
        src = ei[(size_t)stride * e];
        tgt = ei[(size_t)stride * (N_EDGES + e)];
    } else {
        src = tgt = e - N_EDGES;
    }
    int pos = atomicAdd(&cursor[tgt], 1);
    ebuf[rowst[tgt] + pos] = ((unsigned int)e << 14) | (unsigned int)src;
}

// ---------------------------------------------------------------------------
// Gather-aggregate from bf16 xs: agg[n,:] = sum_e alpha_e * xs[src_e,:].
// Thread t owns cols 2t, 2t+1 (one ushort2 load/edge); head = t>>7.
// 4-edge manual unroll for memory-level parallelism.
// ---------------------------------------------------------------------------
__global__ __launch_bounds__(256)
void agg_kernel(const ushort* __restrict__ xs_b,
                const float* __restrict__ wbuf, const float* __restrict__ zbuf,
                const int* __restrict__ rowst, const unsigned int* __restrict__ ebuf,
                float* __restrict__ agg)
{
    const int n = blockIdx.x;
    const int t = threadIdx.x;
    const int h = t >> 7;                     // head for cols 2t, 2t+1
    const float inv = 1.0f / zbuf[n * 2 + h];
    float acc0 = 0.f, acc1 = 0.f;
    const int beg = rowst[n], end = rowst[n + 1];
    int j = beg;
    for (; j + 3 < end; j += 4) {
        unsigned pk0 = ebuf[j],     pk1 = ebuf[j + 1];
        unsigned pk2 = ebuf[j + 2], pk3 = ebuf[j + 3];
        float w0 = wbuf[(pk0 >> 14) * 2 + h];
        float w1 = wbuf[(pk1 >> 14) * 2 + h];
        float w2 = wbuf[(pk2 >> 14) * 2 + h];
        float w3 = wbuf[(pk3 >> 14) * 2 + h];
        ushort2 x0 = *reinterpret_cast<const ushort2*>(&xs_b[(size_t)(pk0 & 0x3FFFu) * DIM_GAT + 2 * t]);
        ushort2 x1 = *reinterpret_cast<const ushort2*>(&xs_b[(size_t)(pk1 & 0x3FFFu) * DIM_GAT + 2 * t]);
        ushort2 x2 = *reinterpret_cast<const ushort2*>(&xs_b[(size_t)(pk2 & 0x3FFFu) * DIM_GAT + 2 * t]);
        ushort2 x3 = *reinterpret_cast<const ushort2*>(&xs_b[(size_t)(pk3 & 0x3FFFu) * DIM_GAT + 2 * t]);
        float a0 = w0 * inv, a1 = w1 * inv, a2 = w2 * inv, a3 = w3 * inv;
        acc0 = fmaf(bf2f(x0.x), a0, acc0); acc1 = fmaf(bf2f(x0.y), a0, acc1);
        acc0 = fmaf(bf2f(x1.x), a1, acc0); acc1 = fmaf(bf2f(x1.y), a1, acc1);
        acc0 = fmaf(bf2f(x2.x), a2, acc0); acc1 = fmaf(bf2f(x2.y), a2, acc1);
        acc0 = fmaf(bf2f(x3.x), a3, acc0); acc1 = fmaf(bf2f(x3.y), a3, acc1);
    }
    for (; j < end; ++j) {
        unsigned pk = ebuf[j];
        float w = wbuf[(pk >> 14) * 2 + h];
        ushort2 x = *reinterpret_cast<const ushort2*>(&xs_b[(size_t)(pk & 0x3FFFu) * DIM_GAT + 2 * t]);
        float a = w * inv;
        acc0 = fmaf(bf2f(x.x), a, acc0);
        acc1 = fmaf(bf2f(x.y), a, acc1);
    }
    agg[(size_t)n * DIM_GAT + 2 * t]     = acc0;
    agg[(size_t)n * DIM_GAT + 2 * t + 1] = acc1;
}

// ---------------------------------------------------------------------------
extern "C" void kernel_launch(void* const* d_in, const int* in_sizes, int n_in,
                              void* d_out, int out_size, void* d_ws, size_t ws_size,
                              hipStream_t stream)
{
    const float* x        = (const float*)d_in[0];
    const int*   ei       = (const int*)  d_in[1];
    const float* enc_w1   = (const float*)d_in[3];
    const float* enc_b1   = (const float*)d_in[4];
    const float* ln_g     = (const float*)d_in[5];
    const float* ln_b     = (const float*)d_in[6];
    const float* enc_w2   = (const float*)d_in[7];
    const float* enc_b2   = (const float*)d_in[8];
    const float* gat_w    = (const float*)d_in[9];
    const float* att_src  = (const float*)d_in[10];
    const float* att_dst  = (const float*)d_in[11];
    const float* gat_bias = (const float*)d_in[12];
    const float* skip_w   = (const float*)d_in[13];
    const float* skip_b   = (const float*)d_in[14];
    const float* dec_w1   = (const float*)d_in[15];
    const float* dec_b1   = (const float*)d_in[16];
    const float* dec_w2   = (const float*)d_in[17];
    const float* dec_b2   = (const float*)d_in[18];
    float* y = (float*)d_out;

    // -------- workspace layout (floats); overlays are phase-disjoint -------
    float* ws = (float*)d_ws;
    // R0 overlay [0, 5242880):
    //   enc phase: h1ln_hi/lo ushort [10112*256] (at +2560000, as before)
    //   gat phase: xs_b ushort [10112*512] at base (h1ln dead after enc2)
    //   skip phase: outb_hi ushort [8192*512] (xs_b dead after agg)
    ushort* h1ln_hi = (ushort*)(ws + 2560000);
    ushort* h1ln_lo = h1ln_hi + (size_t)MPAD * DIM_H;
    ushort* xs_b    = (ushort*)ws;
    ushort* outb_hi = (ushort*)ws;
    // B: h hi/lo (live enc2 -> skip)
    ushort* h_hi = (ushort*)(ws + 5242880);
    ushort* h_lo = h_hi + (size_t)MPAD * DIM_H;
    // D: agg fp32
    float* agg = ws + 7842880;
    // F: split weights (ushort)
    ushort* wsp = (ushort*)(ws + 12037184);
    ushort* w2h = wsp;
    ushort* w2l = w2h + 65536;
    ushort* gwh = w2l + 65536;
    ushort* gwl = gwh + 131072;
    ushort* swh = gwl + 131072;
    ushort* swl = swh + 131072;
    ushort* d1h = swl + 131072;
    ushort* d1l = d1h + 524288;
    // S: edge/attention scratch. asrc..cursor contiguous for a single memset.
    float* S      = ws + 12889152;
    float* asrc   = S;                        // [10000,2]
    float* adst   = S + 20000;                // [10000,2]
    float* zbuf   = S + 40000;                // [10000,2]
    int*   counts = (int*)(S + 60000);        // [10000]
    int*   cursor = counts + 10000;           // [10000]
    float* wbuf   = S + 80000;                // [170000,2]
    int*   rowst  = (int*)(S + 420000);       // [10001]
    unsigned int* ebuf = (unsigned int*)(rowst + 10001); // [170000]
    int*   eflag  = (int*)(ebuf + 170000);    // [1]

    // zero asrc/adst/zbuf/counts/cursor (contiguous 80000 words) + y
    hipMemsetAsync(asrc, 0, 80000 * sizeof(float), stream);
    hipMemsetAsync(y, 0, (size_t)NBATCH * sizeof(float), stream);

    // detect + all weight splits in one launch
    prep_kernel<<<3328, 256, 0, stream>>>(
        ei, eflag,
        enc_w2, w2h, w2l, gat_w, gwh, gwl,
        skip_w, swh, swl, dec_w1, d1h, d1l);

    // enc1 + LN + ReLU + split, fused
    enc1_ln_kernel<<<157, 256, 0, stream>>>(
        x, enc_w1, enc_b1, ln_g, ln_b, h1ln_hi, h1ln_lo);
    // enc2 (MFMA): h = h1ln @ enc_w2^T + b2 -> h hi/lo
    mgemm<1><<<dim3(79, 2), 256, 0, stream>>>(
        h1ln_hi, h1ln_lo, w2h, w2l, enc_b2, nullptr, nullptr,
        nullptr, h_hi, h_lo, nullptr, nullptr, nullptr, nullptr, nullptr,
        N_NODES, DIM_H, DIM_H);
    // gat lin (MFMA): xs_b = bf16(h @ gat_w^T), attn coefs fused -> asrc/adst
    mgemm<0><<<dim3(79, 4), 256, 0, stream>>>(
        h_hi, h_lo, gwh, gwl, att_src, att_dst, nullptr,
        nullptr, xs_b, nullptr, nullptr, nullptr, asrc, adst, nullptr,
        N_NODES, DIM_GAT, DIM_H);
    // edge weights + CSR + aggregate
    edge_w_kernel<<<(E_TOT + 255) / 256, 256, 0, stream>>>(
        ei, eflag, asrc, adst, wbuf, zbuf, counts);
    scan_kernel<<<1, 1024, 0, stream>>>(counts, rowst);
    scatter_kernel<<<(E_TOT + 255) / 256, 256, 0, stream>>>(
        ei, eflag, rowst, cursor, ebuf);
    agg_kernel<<<NBATCH, 256, 0, stream>>>(xs_b, wbuf, zbuf, rowst, ebuf, agg);
    // skip (MFMA): outb = elu(agg + gat_bias + h @ skip_w^T + skip_b) -> hi only
    mgemm<2><<<dim3(64, 4), 256, 0, stream>>>(
        h_hi, h_lo, swh, swl, skip_b, gat_bias, agg,
        nullptr, outb_hi, nullptr, nullptr, nullptr, nullptr, nullptr, nullptr,
        NBATCH, DIM_GAT, DIM_H);
    // dec1 (MFMA, 2-pass) + fused dec2: y += leaky(outb@dec_w1^T+b1)@dec_w2^T+b2
    mgemm<3><<<dim3(64, 8), 256, 0, stream>>>(
        outb_hi, nullptr, d1h, d1l, dec_b1, nullptr, nullptr,
        nullptr, nullptr, nullptr, dec_w2, dec_b2, nullptr, nullptr, y,
        NBATCH, DIM_DEC, DIM_GAT);
}